// Round 1
// baseline (554.284 us; speedup 1.0000x reference)
//
#include <hip/hip_runtime.h>

// 4-layer MLP, fused: 13 -> 256 -> 256 -> 256 -> 80, ReLU on first three.
// M = 64*2048 = 131072 rows. One workgroup = 64 rows (lane = row), 4 waves
// split output columns. Activations in one padded LDS buffer [64][257]
// (65.8 KB -> 2 wg/CU). Weights read as wave-uniform scalar loads.

#define TM   64
#define LDP  257   // padded LDS row stride (floats): bank = (lane + k) % 32, conflict-free

template <int K, int JPW, int JS, bool RELU>
__device__ __forceinline__ void layer(float (*buf)[LDP],
                                      const float* __restrict__ W,
                                      const float* __restrict__ b,
                                      int lane, int wave) {
    const int j0 = wave * JPW;
    float acc[JPW];
#pragma unroll
    for (int jj = 0; jj < JPW; ++jj) acc[jj] = b[j0 + jj];

    for (int k = 0; k < K; ++k) {
        const float h = buf[lane][k];                 // ds_read_b32, conflict-free
        const float* __restrict__ wrow = W + k * JS + j0;  // wave-uniform -> s_load
#pragma unroll
        for (int jj = 0; jj < JPW; ++jj)
            acc[jj] = fmaf(h, wrow[jj], acc[jj]);
    }

    __syncthreads();   // everyone done READING buf before we overwrite it
#pragma unroll
    for (int jj = 0; jj < JPW; ++jj) {
        float v = acc[jj];
        if (RELU) v = fmaxf(v, 0.0f);
        buf[lane][j0 + jj] = v;
    }
    __syncthreads();   // writes visible before next layer reads
}

__global__ __launch_bounds__(256, 2) void mlp4_kernel(
    const float* __restrict__ x,
    const float* __restrict__ W1, const float* __restrict__ b1,
    const float* __restrict__ W2, const float* __restrict__ b2,
    const float* __restrict__ W3, const float* __restrict__ b3,
    const float* __restrict__ W4, const float* __restrict__ b4,
    float* __restrict__ out) {
    __shared__ float buf[TM][LDP];

    const int tid  = threadIdx.x;
    const int lane = tid & 63;
    const int wave = __builtin_amdgcn_readfirstlane(tid >> 6);
    const long m0  = (long)blockIdx.x * TM;

    // Stage x tile: 64 rows x 13 floats, coalesced.
    for (int i = tid; i < TM * 13; i += 256) {
        const int m = i / 13, k = i % 13;
        buf[m][k] = x[(m0 + m) * 13 + k];
    }
    __syncthreads();

    layer<13,  64, 256, true >(buf, W1, b1, lane, wave);  // L1: 13 -> 256
    layer<256, 64, 256, true >(buf, W2, b2, lane, wave);  // L2: 256 -> 256
    layer<256, 64, 256, true >(buf, W3, b3, lane, wave);  // L3: 256 -> 256
    layer<256, 20,  80, false>(buf, W4, b4, lane, wave);  // L4: 256 -> 80 (no ReLU)

    // Store out tile: 64 rows x 80 floats, coalesced.
    for (int i = tid; i < TM * 80; i += 256) {
        out[m0 * 80 + i] = buf[i / 80][i % 80];
    }
}

extern "C" void kernel_launch(void* const* d_in, const int* in_sizes, int n_in,
                              void* d_out, int out_size, void* d_ws, size_t ws_size,
                              hipStream_t stream) {
    const float* x  = (const float*)d_in[0];
    const float* W1 = (const float*)d_in[1];
    const float* b1 = (const float*)d_in[2];
    const float* W2 = (const float*)d_in[3];
    const float* b2 = (const float*)d_in[4];
    const float* W3 = (const float*)d_in[5];
    const float* b3 = (const float*)d_in[6];
    const float* W4 = (const float*)d_in[7];
    const float* b4 = (const float*)d_in[8];
    float* out = (float*)d_out;

    const int M = 64 * 2048;            // 131072 rows
    dim3 grid(M / TM), block(256);      // 2048 workgroups
    hipLaunchKernelGGL(mlp4_kernel, grid, block, 0, stream,
                       x, W1, b1, W2, b2, W3, b3, W4, b4, out);
}

// Round 3
// 106.664 us; speedup vs baseline: 5.1966x; 5.1966x over previous
//
#include <hip/hip_runtime.h>

// Fully-fused 4-layer MLP via f16 MFMA (fp32 accumulate), activations held in
// registers across layers by computing the transposed problem G = H^T:
//   G_{i+1} = relu(W_{i+1}^T * G_i + b)      (A = W^T tiles, B = G tiles)
// C fragment (col = lane&31 = sample) feeds the next layer's B fragment after a
// pack-to-f16 + lane-half exchange (shfl_xor 32). Weights pre-swizzled into
// A-fragment order (f16, zero-padded K 13->16, N 80->96) by a prep kernel.

typedef _Float16 half_t;
typedef _Float16 half8 __attribute__((ext_vector_type(8)));
typedef float f32x16 __attribute__((ext_vector_type(16)));
typedef unsigned int uint4v __attribute__((ext_vector_type(4)));

#define M_TOTAL (64*2048)

// ws layout in half_t units (weights only: 312 frag-blocks * 512 halves = 320 KB)
#define W1P_OFF 0                        // 8 frag-blocks   (ks=1, nt=8)
#define W2P_OFF (W1P_OFF + 8*512)        // 128 frag-blocks (ks=16, nt=8)
#define W3P_OFF (W2P_OFF + 128*512)
#define W4P_OFF (W3P_OFF + 128*512)      // 48 frag-blocks  (ks=16, nt=3)

// ---------------- prep kernel ----------------

// One thread per output half. Fragment layout per (ks,nt) block:
//   wp[((ks*NT+nt)*64 + lane)*8 + j] = W[ks*16 + (lane>>5)*8 + j][nt*32 + (lane&31)]
__global__ void prep_w(const float* __restrict__ W1, const float* __restrict__ W2,
                       const float* __restrict__ W3, const float* __restrict__ W4,
                       half_t* __restrict__ wp) {
    int tid = blockIdx.x * 256 + threadIdx.x;
    if (tid >= 312 * 512) return;
    int blk = tid >> 9, r = tid & 511;
    int lane = r >> 3, j = r & 7;
    const float* W; int K, N, NT, lb;
    if (blk < 8)        { W = W1; K = 13;  N = 256; NT = 8; lb = blk; }
    else if (blk < 136) { W = W2; K = 256; N = 256; NT = 8; lb = blk - 8; }
    else if (blk < 264) { W = W3; K = 256; N = 256; NT = 8; lb = blk - 136; }
    else                { W = W4; K = 256; N = 80;  NT = 3; lb = blk - 264; }
    int ks = lb / NT, nt = lb % NT;
    int k = ks * 16 + (lane >> 5) * 8 + j;
    int n = nt * 32 + (lane & 31);
    float v = (k < K && n < N) ? W[k * N + n] : 0.f;
    wp[tid] = (half_t)v;
}

// ---------------- main kernel ----------------

__device__ __forceinline__ half8 ld_frag(const half_t* p) {
    return *reinterpret_cast<const half8*>(p);
}

__device__ __forceinline__ unsigned int pkrtz(float a, float b) {
    auto p = __builtin_amdgcn_cvt_pkrtz(a, b);   // __fp16 ext_vector(2)
    return __builtin_bit_cast(unsigned int, p);
}

// One layer: 8 output feature-tiles (256 features), K = NKS*16.
// Bin/Bout: per k-step 4 packed f16x2 words (B-fragment form).
template <int NKS, bool RELU>
__device__ __forceinline__ void dense_layer(
    const unsigned int (&Bin)[16][4], unsigned int (&Bout)[16][4],
    const half_t* __restrict__ Wp, const float* bias, int lane, bool hi)
{
#pragma unroll
    for (int nt = 0; nt < 8; ++nt) {
        f32x16 acc = {};
#pragma unroll
        for (int ks = 0; ks < NKS; ++ks) {
            half8 a = ld_frag(Wp + (((ks * 8 + nt) * 64 + lane) << 3));
            uint4v bw = { Bin[ks][0], Bin[ks][1], Bin[ks][2], Bin[ks][3] };
            half8 b = __builtin_bit_cast(half8, bw);
            acc = __builtin_amdgcn_mfma_f32_32x32x16_f16(a, b, acc, 0, 0, 0);
        }
#pragma unroll
        for (int s = 0; s < 2; ++s) {
            float v[8];
#pragma unroll
            for (int q = 0; q < 8; ++q) {
                // C row r = (reg&3) + 8*(reg>>2) + 4*(lane>=32), reg = 8s+q
                // => feature f = nt*32 + 16s + (q&3) + 8*(q>>2) + 4*hi
                int f = (q & 3) + 8 * (q >> 2) + (hi ? 4 : 0);
                float t = acc[8 * s + q] + bias[nt * 32 + 16 * s + f];
                v[q] = RELU ? fmaxf(t, 0.f) : t;
            }
            unsigned int P0 = pkrtz(v[0], v[1]);   // lo:(0,1)  hi:(4,5)    (+16s)
            unsigned int P1 = pkrtz(v[2], v[3]);   // lo:(2,3)  hi:(6,7)
            unsigned int P2 = pkrtz(v[4], v[5]);   // lo:(8,9)  hi:(12,13)
            unsigned int P3 = pkrtz(v[6], v[7]);   // lo:(10,11) hi:(14,15)
            unsigned int t0 = __shfl_xor(P0, 32);
            unsigned int t1 = __shfl_xor(P1, 32);
            unsigned int t2 = __shfl_xor(P2, 32);
            unsigned int t3 = __shfl_xor(P3, 32);
            // B word w covers k = (hi?8:0) + 2w, 2w+1
            Bout[2 * nt + s][0] = hi ? t2 : P0;
            Bout[2 * nt + s][1] = hi ? t3 : P1;
            Bout[2 * nt + s][2] = hi ? P2 : t0;
            Bout[2 * nt + s][3] = hi ? P3 : t1;
        }
    }
}

__device__ __forceinline__ void out_layer(
    const unsigned int (&Bin)[16][4], const half_t* __restrict__ Wp,
    const float* bias, float* obuf_w, int lane, bool hi)
{
#pragma unroll
    for (int nt = 0; nt < 3; ++nt) {
        f32x16 acc = {};
#pragma unroll
        for (int ks = 0; ks < 16; ++ks) {
            half8 a = ld_frag(Wp + (((ks * 3 + nt) * 64 + lane) << 3));
            uint4v bw = { Bin[ks][0], Bin[ks][1], Bin[ks][2], Bin[ks][3] };
            half8 b = __builtin_bit_cast(half8, bw);
            acc = __builtin_amdgcn_mfma_f32_32x32x16_f16(a, b, acc, 0, 0, 0);
        }
#pragma unroll
        for (int reg = 0; reg < 16; ++reg) {
            int rr = (reg & 3) + 8 * (reg >> 2) + (hi ? 4 : 0);
            obuf_w[(lane & 31) * 97 + nt * 32 + rr] = acc[reg] + bias[nt * 32 + rr];
        }
    }
}

__global__ __launch_bounds__(256, 2) void mlp_mfma(
    const float* __restrict__ x,
    const half_t* __restrict__ W1p, const half_t* __restrict__ W2p,
    const half_t* __restrict__ W3p, const half_t* __restrict__ W4p,
    const float* __restrict__ b1, const float* __restrict__ b2,
    const float* __restrict__ b3, const float* __restrict__ b4,
    float* __restrict__ out)
{
    __shared__ float bias_lds[864];          // b1|b2|b3 (256 each) | b4 (96, padded)
    __shared__ float obuf[4 * 32 * 97];      // per-wave output transpose buffer

    int tid = threadIdx.x;
    bias_lds[tid] = b1[tid];
    bias_lds[256 + tid] = b2[tid];
    bias_lds[512 + tid] = b3[tid];
    if (tid < 96) bias_lds[768 + tid] = (tid < 80) ? b4[tid] : 0.f;
    __syncthreads();

    int lane = tid & 63;
    int wave = tid >> 6;
    bool hi = lane >= 32;
    int m0 = (blockIdx.x * 4 + wave) * 32;   // 32 samples per wave

    unsigned int BA[16][4], BB[16][4];

    // Layer-1 B fragment directly from fp32 x: lane holds x[m][k], k = (hi?8:0)+j
    {
        const float* xp = x + (long)(m0 + (lane & 31)) * 13;
        float xv[8];
        if (!hi) {
#pragma unroll
            for (int j = 0; j < 8; ++j) xv[j] = xp[j];
        } else {
#pragma unroll
            for (int j = 0; j < 5; ++j) xv[j] = xp[8 + j];
            xv[5] = xv[6] = xv[7] = 0.f;
        }
        BA[0][0] = pkrtz(xv[0], xv[1]);
        BA[0][1] = pkrtz(xv[2], xv[3]);
        BA[0][2] = pkrtz(xv[4], xv[5]);
        BA[0][3] = pkrtz(xv[6], xv[7]);
    }

    dense_layer<1,  true>(BA, BB, W1p, bias_lds,       lane, hi);  // 13->256
    dense_layer<16, true>(BB, BA, W2p, bias_lds + 256, lane, hi);  // 256->256
    dense_layer<16, true>(BA, BB, W3p, bias_lds + 512, lane, hi);  // 256->256
    out_layer            (BB, W4p, bias_lds + 768, obuf + wave * 3104, lane, hi);

    __syncthreads();

    // coalesced store: 32 rows x 80 floats per wave
    const float* ob = obuf + wave * 3104;
    long base = (long)m0 * 80;
#pragma unroll
    for (int i = 0; i < 40; ++i) {
        int idx = i * 64 + lane;
        out[base + idx] = ob[(idx / 80) * 97 + idx % 80];
    }
}

// ---------------- launch ----------------

extern "C" void kernel_launch(void* const* d_in, const int* in_sizes, int n_in,
                              void* d_out, int out_size, void* d_ws, size_t ws_size,
                              hipStream_t stream) {
    const float* x  = (const float*)d_in[0];
    const float* W1 = (const float*)d_in[1];
    const float* b1 = (const float*)d_in[2];
    const float* W2 = (const float*)d_in[3];
    const float* b2 = (const float*)d_in[4];
    const float* W3 = (const float*)d_in[5];
    const float* b3 = (const float*)d_in[6];
    const float* W4 = (const float*)d_in[7];
    const float* b4 = (const float*)d_in[8];
    float* out = (float*)d_out;

    half_t* wp = (half_t*)d_ws;

    hipLaunchKernelGGL(prep_w, dim3(624), dim3(256), 0, stream, W1, W2, W3, W4, wp);
    hipLaunchKernelGGL(mlp_mfma, dim3(M_TOTAL / 128), dim3(256), 0, stream,
                       x,
                       wp + W1P_OFF, wp + W2P_OFF, wp + W3P_OFF, wp + W4P_OFF,
                       b1, b2, b3, b4, out);
}

// Round 4
// 60.852 us; speedup vs baseline: 9.1087x; 1.7528x over previous
//
#include <hip/hip_runtime.h>

// Fully-fused 4-layer MLP via f16 MFMA (fp32 accumulate), transposed problem
// G = H^T so activations live in registers across layers (B operand), and
// per-layer weight strips (A operand, pre-swizzled to fragment order) are
// double-buffer staged into LDS with global_load_lds, shared by 4 waves.

typedef _Float16 half_t;
typedef _Float16 half8 __attribute__((ext_vector_type(8)));
typedef float f32x16 __attribute__((ext_vector_type(16)));
typedef unsigned int uint4v __attribute__((ext_vector_type(4)));

#define M_TOTAL (64*2048)

// ---------------- prep kernel ----------------
// Strip-ordered fragment layout (halves), 512 halves per fragment-block:
//   L1: blocks 0..7     -> nt               (ks = 0, K padded 13->16)
//   L2: blocks 8..135   -> nt*16 + ks
//   L3: blocks 136..263 -> nt*16 + ks
//   L4: blocks 264..311 -> nt*16 + ks       (N padded 80->96)
// Within a block: wp[blk*512 + lane*8 + j] = W[ks*16 + (lane>>5)*8 + j][nt*32 + (lane&31)]
__global__ void prep_w(const float* __restrict__ W1, const float* __restrict__ W2,
                       const float* __restrict__ W3, const float* __restrict__ W4,
                       half_t* __restrict__ wp) {
    int tid = blockIdx.x * 256 + threadIdx.x;
    if (tid >= 312 * 512) return;
    int blk = tid >> 9, r = tid & 511;
    int lane = r >> 3, j = r & 7;
    const float* W; int K, N, nt, ks;
    if (blk < 8)        { W = W1; K = 13;  N = 256; nt = blk;              ks = 0; }
    else if (blk < 136) { W = W2; K = 256; N = 256; nt = (blk-8) >> 4;     ks = (blk-8) & 15; }
    else if (blk < 264) { W = W3; K = 256; N = 256; nt = (blk-136) >> 4;   ks = (blk-136) & 15; }
    else                { W = W4; K = 256; N = 80;  nt = (blk-264) >> 4;   ks = (blk-264) & 15; }
    int k = ks * 16 + (lane >> 5) * 8 + j;
    int n = nt * 32 + (lane & 31);
    float v = (k < K && n < N) ? W[k * N + n] : 0.f;
    wp[tid] = (half_t)v;
}

// ---------------- main kernel ----------------

__device__ __forceinline__ unsigned int pkrtz(float a, float b) {
    auto p = __builtin_amdgcn_cvt_pkrtz(a, b);
    return __builtin_bit_cast(unsigned int, p);
}

typedef const __attribute__((address_space(1))) unsigned int guint_t;
typedef __attribute__((address_space(3))) unsigned int luint_t;

// Stage `bytes` (multiple of 4096) from g into LDS l: 256 threads x 16 B rounds.
// LDS dest is wave-uniform base + lane*16 (global_load_lds semantics).
__device__ __forceinline__ void stage_strip(const half_t* __restrict__ g,
                                            half_t* l, int bytes, int tid) {
    const char* gc = (const char*)g;
    char* lc = (char*)l;
    const int go = tid * 16;             // per-lane global offset
    const int lo = (tid >> 6) << 10;     // wave-uniform LDS offset (wave*1024)
#pragma unroll
    for (int r = 0; r < bytes; r += 4096) {
        __builtin_amdgcn_global_load_lds((guint_t*)(gc + r + go),
                                         (luint_t*)(lc + r + lo), 16, 0, 0);
    }
}

// strip index -> offset in wp (halves); folds at compile time after unroll
__device__ __forceinline__ int strip_off(int s) {
    if (s == 0)  return 0;
    if (s <= 8)  return (8   + (s - 1)  * 16) * 512;
    if (s <= 16) return (136 + (s - 9)  * 16) * 512;
    return (264 + (s - 17) * 16) * 512;
}

// One 32-feature output tile: K = NKS*16 from LDS strip, repack into 2 B-words.
template <int NKS, bool RELU>
__device__ __forceinline__ void dense_tile(const half_t* astrip,
                                           const unsigned int (&Bin)[16][4],
                                           unsigned int (*Bout)[4],      // -> B words s=0,1
                                           const float* biasnt, int lane, bool hi)
{
    f32x16 acc = {};
#pragma unroll
    for (int ks = 0; ks < NKS; ++ks) {
        half8 a = *(const half8*)(astrip + ((ks * 64 + lane) << 3));
        uint4v bw = { Bin[ks][0], Bin[ks][1], Bin[ks][2], Bin[ks][3] };
        acc = __builtin_amdgcn_mfma_f32_32x32x16_f16(a, __builtin_bit_cast(half8, bw),
                                                     acc, 0, 0, 0);
    }
#pragma unroll
    for (int s = 0; s < 2; ++s) {
        float v[8];
#pragma unroll
        for (int q = 0; q < 8; ++q) {
            // C row = (reg&3) + 8*(reg>>2) + 4*(lane>=32), reg = 8s+q
            int f = (q & 3) + 8 * (q >> 2) + (hi ? 4 : 0);
            float t = acc[8 * s + q] + biasnt[16 * s + f];
            v[q] = RELU ? fmaxf(t, 0.f) : t;
        }
        unsigned int P0 = pkrtz(v[0], v[1]);
        unsigned int P1 = pkrtz(v[2], v[3]);
        unsigned int P2 = pkrtz(v[4], v[5]);
        unsigned int P3 = pkrtz(v[6], v[7]);
        unsigned int t0 = __shfl_xor(P0, 32);
        unsigned int t1 = __shfl_xor(P1, 32);
        unsigned int t2 = __shfl_xor(P2, 32);
        unsigned int t3 = __shfl_xor(P3, 32);
        Bout[s][0] = hi ? t2 : P0;
        Bout[s][1] = hi ? t3 : P1;
        Bout[s][2] = hi ? P2 : t0;
        Bout[s][3] = hi ? P3 : t1;
    }
}

__global__ __launch_bounds__(256, 2) void mlp_mfma(
    const float* __restrict__ x, const half_t* __restrict__ wp,
    const float* __restrict__ b1, const float* __restrict__ b2,
    const float* __restrict__ b3, const float* __restrict__ b4,
    float* __restrict__ out)
{
    __shared__ half_t wbuf[2][8192];     // double-buffered weight strips (2 x 16 KB)
    __shared__ float  bias_lds[864];     // b1|b2|b3 (256 each) | b4 (96, padded)
    __shared__ float  obuf[4][32 * 33];  // per-wave 32x32 output transpose tile

    const int tid  = threadIdx.x;
    const int lane = tid & 63;
    const int wave = tid >> 6;
    const bool hi  = lane >= 32;
    const int m0   = (blockIdx.x * 4 + wave) * 32;

    bias_lds[tid] = b1[tid];
    bias_lds[256 + tid] = b2[tid];
    bias_lds[512 + tid] = b3[tid];
    if (tid < 96) bias_lds[768 + tid] = (tid < 80) ? b4[tid] : 0.f;

    stage_strip(wp + strip_off(0), wbuf[0], 8192, tid);   // L1 (all 8 nt, 8 KB)

    unsigned int BA[16][4], BB[16][4];

    // Layer-1 B fragment from fp32 x: lane holds x[m][k], k = (hi?8:0)+j
    {
        const float* xp = x + (long)(m0 + (lane & 31)) * 13;
        float xv[8];
        if (!hi) {
#pragma unroll
            for (int j = 0; j < 8; ++j) xv[j] = xp[j];
        } else {
#pragma unroll
            for (int j = 0; j < 5; ++j) xv[j] = xp[8 + j];
            xv[5] = xv[6] = xv[7] = 0.f;
        }
        BA[0][0] = pkrtz(xv[0], xv[1]);
        BA[0][1] = pkrtz(xv[2], xv[3]);
        BA[0][2] = pkrtz(xv[4], xv[5]);
        BA[0][3] = pkrtz(xv[6], xv[7]);
    }

    __syncthreads();   // strip 0 + bias in LDS (syncthreads drains vmcnt)

    // ---- L1: strip 0 (8 nt-blocks in one strip), 13->256 ----
    stage_strip(wp + strip_off(1), wbuf[1], 16384, tid);
#pragma unroll
    for (int nt = 0; nt < 8; ++nt)
        dense_tile<1, true>(&wbuf[0][nt * 512], BA, &BB[2 * nt],
                            bias_lds + nt * 32, lane, hi);
    __syncthreads();

    // ---- L2: strips 1..8, 256->256 ----
#pragma unroll
    for (int nt = 0; nt < 8; ++nt) {
        stage_strip(wp + strip_off(2 + nt), wbuf[(2 + nt) & 1], 16384, tid);
        dense_tile<16, true>(&wbuf[(1 + nt) & 1][0], BB, &BA[2 * nt],
                             bias_lds + 256 + nt * 32, lane, hi);
        __syncthreads();
    }

    // ---- L3: strips 9..16, 256->256 ----
#pragma unroll
    for (int nt = 0; nt < 8; ++nt) {
        stage_strip(wp + strip_off(10 + nt), wbuf[(10 + nt) & 1], 16384, tid);
        dense_tile<16, true>(&wbuf[(9 + nt) & 1][0], BA, &BB[2 * nt],
                             bias_lds + 512 + nt * 32, lane, hi);
        __syncthreads();
    }

    // ---- L4: strips 17..19, 256->80 (no ReLU), per-nt transpose + store ----
#pragma unroll
    for (int nt = 0; nt < 3; ++nt) {
        if (nt < 2) stage_strip(wp + strip_off(18 + nt), wbuf[(18 + nt) & 1], 16384, tid);
        const half_t* astrip = &wbuf[(17 + nt) & 1][0];
        f32x16 acc = {};
#pragma unroll
        for (int ks = 0; ks < 16; ++ks) {
            half8 a = *(const half8*)(astrip + ((ks * 64 + lane) << 3));
            uint4v bw = { BB[ks][0], BB[ks][1], BB[ks][2], BB[ks][3] };
            acc = __builtin_amdgcn_mfma_f32_32x32x16_f16(a, __builtin_bit_cast(half8, bw),
                                                         acc, 0, 0, 0);
        }
#pragma unroll
        for (int reg = 0; reg < 16; ++reg) {
            int rr = (reg & 3) + 8 * (reg >> 2) + (hi ? 4 : 0);
            obuf[wave][(lane & 31) * 33 + rr] = acc[reg] + bias_lds[768 + nt * 32 + rr];
        }
        __syncthreads();   // cross-lane obuf visibility (+ drains next strip's stage)
#pragma unroll
        for (int i = 0; i < 16; ++i) {
            int idx = i * 64 + lane;          // 32 rows x 32 cols
            int m = idx >> 5, c = idx & 31;
            int f = nt * 32 + c;
            if (f < 80)
                out[(long)(m0 + m) * 80 + f] = obuf[wave][m * 33 + c];
        }
        __syncthreads();   // reads done before next nt overwrites obuf
    }
}

// ---------------- launch ----------------

extern "C" void kernel_launch(void* const* d_in, const int* in_sizes, int n_in,
                              void* d_out, int out_size, void* d_ws, size_t ws_size,
                              hipStream_t stream) {
    const float* x  = (const float*)d_in[0];
    const float* W1 = (const float*)d_in[1];
    const float* b1 = (const float*)d_in[2];
    const float* W2 = (const float*)d_in[3];
    const float* b2 = (const float*)d_in[4];
    const float* W3 = (const float*)d_in[5];
    const float* b3 = (const float*)d_in[6];
    const float* W4 = (const float*)d_in[7];
    const float* b4 = (const float*)d_in[8];
    float* out = (float*)d_out;

    half_t* wp = (half_t*)d_ws;

    hipLaunchKernelGGL(prep_w, dim3(624), dim3(256), 0, stream, W1, W2, W3, W4, wp);
    hipLaunchKernelGGL(mlp_mfma, dim3(M_TOTAL / 128), dim3(256), 0, stream,
                       x, wp, b1, b2, b3, b4, out);
}

// Round 5
// 53.728 us; speedup vs baseline: 10.3164x; 1.1326x over previous
//
#include <hip/hip_runtime.h>

// Fully-fused 4-layer MLP via f16 MFMA (fp32 accumulate), transposed problem
// G = H^T: activations live in registers across all layers (B operand).
// Weight strips (A operand, pre-swizzled) are 3-deep pipelined into LDS via
// global_load_lds with COUNTED vmcnt barriers (s_waitcnt vmcnt(4) + s_barrier,
// never vmcnt(0) in the main loop). L4 stores straight from the C fragment.

typedef _Float16 half_t;
typedef _Float16 half8 __attribute__((ext_vector_type(8)));
typedef float f32x16 __attribute__((ext_vector_type(16)));
typedef unsigned int uint4v __attribute__((ext_vector_type(4)));
typedef int int2v __attribute__((ext_vector_type(2)));

#define M_TOTAL (64*2048)

// ---------------- prep kernel ----------------
// Strip-ordered fragment layout (halves), 512 halves per fragment-block:
//   L1: blocks 0..7     (strip 0: all 8 nt, ks=0, K padded 13->16)
//   L2: blocks 8..135   (strips 1..8:  nt*16 + ks)
//   L3: blocks 136..263 (strips 9..16)
//   L4: blocks 264..311 (strips 17..19, N padded 80->96)
// Within a block: wp[blk*512 + lane*8 + j] = W[ks*16 + (lane>>5)*8 + j][nt*32 + (lane&31)]
__global__ void prep_w(const float* __restrict__ W1, const float* __restrict__ W2,
                       const float* __restrict__ W3, const float* __restrict__ W4,
                       half_t* __restrict__ wp) {
    int tid = blockIdx.x * 256 + threadIdx.x;
    if (tid >= 312 * 512) return;
    int blk = tid >> 9, r = tid & 511;
    int lane = r >> 3, j = r & 7;
    const float* W; int K, N, nt, ks;
    if (blk < 8)        { W = W1; K = 13;  N = 256; nt = blk;              ks = 0; }
    else if (blk < 136) { W = W2; K = 256; N = 256; nt = (blk-8) >> 4;     ks = (blk-8) & 15; }
    else if (blk < 264) { W = W3; K = 256; N = 256; nt = (blk-136) >> 4;   ks = (blk-136) & 15; }
    else                { W = W4; K = 256; N = 80;  nt = (blk-264) >> 4;   ks = (blk-264) & 15; }
    int k = ks * 16 + (lane >> 5) * 8 + j;
    int n = nt * 32 + (lane & 31);
    float v = (k < K && n < N) ? W[k * N + n] : 0.f;
    wp[tid] = (half_t)v;
}

// ---------------- main kernel ----------------

__device__ __forceinline__ unsigned int pkrtz(float a, float b) {
    auto p = __builtin_amdgcn_cvt_pkrtz(a, b);
    return __builtin_bit_cast(unsigned int, p);
}

typedef const __attribute__((address_space(1))) unsigned int guint_t;
typedef __attribute__((address_space(3))) unsigned int luint_t;

// Stage `bytes` (multiple of 4096) from g into LDS l. 256 threads x 16 B.
__device__ __forceinline__ void stage_strip(const half_t* __restrict__ g,
                                            half_t* l, int bytes, int tid) {
    const char* gc = (const char*)g;
    char* lc = (char*)l;
    const int go = tid * 16;             // per-lane global offset
    const int lo = (tid >> 6) << 10;     // wave-uniform LDS offset (wave*1024)
#pragma unroll
    for (int r = 0; r < bytes; r += 4096) {
        __builtin_amdgcn_global_load_lds((guint_t*)(gc + r + go),
                                         (luint_t*)(lc + r + lo), 16, 0, 0);
    }
}

// strip index -> offset in wp (halves); folds at compile time after unroll
__device__ __forceinline__ int strip_off(int s) {
    if (s == 0)  return 0;
    if (s <= 8)  return (8   + (s - 1)  * 16) * 512;
    if (s <= 16) return (136 + (s - 9)  * 16) * 512;
    return (264 + (s - 17) * 16) * 512;
}

// Counted-vmcnt pipeline barrier: keep newest stage's loads in flight.
#define PIPE_BAR(Nstr) do {                                   \
    asm volatile("s_waitcnt vmcnt(" Nstr ")" ::: "memory");   \
    __builtin_amdgcn_sched_barrier(0);                        \
    __builtin_amdgcn_s_barrier();                             \
    __builtin_amdgcn_sched_barrier(0);                        \
} while (0)

// One 32-feature output tile: K = NKS*16 from LDS strip, repack into 2 B-words.
template <int NKS, bool RELU>
__device__ __forceinline__ void dense_tile(const half_t* astrip,
                                           const unsigned int (&Bin)[16][4],
                                           unsigned int (*Bout)[4],
                                           const float* biasnt, int lane, bool hi)
{
    f32x16 acc = {};
#pragma unroll
    for (int ks = 0; ks < NKS; ++ks) {
        half8 a = *(const half8*)(astrip + ((ks * 64 + lane) << 3));
        uint4v bw = { Bin[ks][0], Bin[ks][1], Bin[ks][2], Bin[ks][3] };
        acc = __builtin_amdgcn_mfma_f32_32x32x16_f16(a, __builtin_bit_cast(half8, bw),
                                                     acc, 0, 0, 0);
    }
#pragma unroll
    for (int s = 0; s < 2; ++s) {
        float v[8];
#pragma unroll
        for (int q = 0; q < 8; ++q) {
            // C row = (reg&3) + 8*(reg>>2) + 4*(lane>=32), reg = 8s+q
            int f = (q & 3) + 8 * (q >> 2) + (hi ? 4 : 0);
            float t = acc[8 * s + q] + biasnt[16 * s + f];
            v[q] = RELU ? fmaxf(t, 0.f) : t;
        }
        unsigned int P0 = pkrtz(v[0], v[1]);   // lo:(0,1)  hi:(4,5)
        unsigned int P1 = pkrtz(v[2], v[3]);   // lo:(2,3)  hi:(6,7)
        unsigned int P2 = pkrtz(v[4], v[5]);   // lo:(8,9)  hi:(12,13)
        unsigned int P3 = pkrtz(v[6], v[7]);   // lo:(10,11) hi:(14,15)
        // One swap fills two B-words: word0=[P0.lo|P2.lo], word2=[P0.hi|P2.hi]
        int2v r02 = __builtin_amdgcn_permlane32_swap((int)P0, (int)P2, false, false);
        int2v r13 = __builtin_amdgcn_permlane32_swap((int)P1, (int)P3, false, false);
        Bout[s][0] = (unsigned int)r02.x;
        Bout[s][1] = (unsigned int)r13.x;
        Bout[s][2] = (unsigned int)r02.y;
        Bout[s][3] = (unsigned int)r13.y;
    }
}

// L4 tile: 32 features, direct global stores from the C fragment.
__device__ __forceinline__ void out_tile(const half_t* astrip,
                                         const unsigned int (&Bin)[16][4],
                                         const float* biasnt, float* __restrict__ out,
                                         int m0, int nt, int lane, bool hi)
{
    f32x16 acc = {};
#pragma unroll
    for (int ks = 0; ks < 16; ++ks) {
        half8 a = *(const half8*)(astrip + ((ks * 64 + lane) << 3));
        uint4v bw = { Bin[ks][0], Bin[ks][1], Bin[ks][2], Bin[ks][3] };
        acc = __builtin_amdgcn_mfma_f32_32x32x16_f16(a, __builtin_bit_cast(half8, bw),
                                                     acc, 0, 0, 0);
    }
    float* orow = out + (long)(m0 + (lane & 31)) * 80 + nt * 32;
#pragma unroll
    for (int reg = 0; reg < 16; ++reg) {
        if (nt == 2 && (reg >> 2) >= 2) continue;   // f = 64+rr < 80 <=> rr < 16
        int rr = (reg & 3) + 8 * (reg >> 2) + (hi ? 4 : 0);
        orow[rr] = acc[reg] + biasnt[rr];
    }
}

__global__ __launch_bounds__(256, 2) void mlp_mfma(
    const float* __restrict__ x, const half_t* __restrict__ wp,
    const float* __restrict__ b1, const float* __restrict__ b2,
    const float* __restrict__ b3, const float* __restrict__ b4,
    float* __restrict__ out)
{
    __shared__ half_t wbuf[3][8192];     // 3-deep strip pipeline (3 x 16 KB)
    __shared__ float  bias_lds[864];     // b1|b2|b3 (256 each) | b4 (96, padded)

    const int tid  = threadIdx.x;
    const int lane = tid & 63;
    const bool hi  = lane >= 32;
    const int m0   = (blockIdx.x * 4 + (tid >> 6)) * 32;   // 32 samples per wave

    bias_lds[tid] = b1[tid];
    bias_lds[256 + tid] = b2[tid];
    bias_lds[512 + tid] = b3[tid];
    if (tid < 96) bias_lds[768 + tid] = (tid < 80) ? b4[tid] : 0.f;

    stage_strip(wp + strip_off(0), wbuf[0], 8192, tid);    // L1 strip (8 KB)
    stage_strip(wp + strip_off(1), wbuf[1], 16384, tid);

    unsigned int BA[16][4], BB[16][4];

    // Layer-1 B fragment from fp32 x: lane holds x[m][k], k = (hi?8:0)+j
    {
        const float* xp = x + (long)(m0 + (lane & 31)) * 13;
        float xv[8];
        if (!hi) {
#pragma unroll
            for (int j = 0; j < 8; ++j) xv[j] = xp[j];
        } else {
#pragma unroll
            for (int j = 0; j < 5; ++j) xv[j] = xp[8 + j];
            xv[5] = xv[6] = xv[7] = 0.f;
        }
        BA[0][0] = pkrtz(xv[0], xv[1]);
        BA[0][1] = pkrtz(xv[2], xv[3]);
        BA[0][2] = pkrtz(xv[4], xv[5]);
        BA[0][3] = pkrtz(xv[6], xv[7]);
    }

    __syncthreads();   // phase-0 entry: bias + strips 0,1 resident

    // ---- Phase 0 / L1: strip 0 (8 nt-blocks), 13->256 ----
    stage_strip(wp + strip_off(2), wbuf[2], 16384, tid);
#pragma unroll
    for (int nt = 0; nt < 8; ++nt)
        dense_tile<1, true>(&wbuf[0][nt * 512], BA, &BB[2 * nt],
                            bias_lds + nt * 32, lane, hi);

    // ---- Phases 1..8 / L2: strips 1..8, 256->256 ----
#pragma unroll
    for (int i = 0; i < 8; ++i) {
        const int k = 1 + i;
        PIPE_BAR("4");                              // strip k landed; k+1 in flight
        stage_strip(wp + strip_off(k + 2), wbuf[(k + 2) % 3], 16384, tid);
        dense_tile<16, true>(&wbuf[k % 3][0], BB, &BA[2 * i],
                             bias_lds + 256 + i * 32, lane, hi);
    }

    // ---- Phases 9..16 / L3: strips 9..16, 256->256 ----
#pragma unroll
    for (int i = 0; i < 8; ++i) {
        const int k = 9 + i;
        PIPE_BAR("4");
        stage_strip(wp + strip_off(k + 2), wbuf[(k + 2) % 3], 16384, tid);
        dense_tile<16, true>(&wbuf[k % 3][0], BA, &BB[2 * i],
                             bias_lds + 512 + i * 32, lane, hi);
    }

    // ---- Phases 17..19 / L4: strips 17..19, 256->80, direct stores ----
#pragma unroll
    for (int i = 0; i < 3; ++i) {
        const int k = 17 + i;
        if (i < 2) PIPE_BAR("4");                   // over-waits stores; safe
        else       PIPE_BAR("0");                   // last strip must be fully landed
        if (i == 0) stage_strip(wp + strip_off(19), wbuf[19 % 3], 16384, tid);
        out_tile(&wbuf[k % 3][0], BB, bias_lds + 768 + i * 32, out, m0, i, lane, hi);
    }
}

// ---------------- launch ----------------

extern "C" void kernel_launch(void* const* d_in, const int* in_sizes, int n_in,
                              void* d_out, int out_size, void* d_ws, size_t ws_size,
                              hipStream_t stream) {
    const float* x  = (const float*)d_in[0];
    const float* W1 = (const float*)d_in[1];
    const float* b1 = (const float*)d_in[2];
    const float* W2 = (const float*)d_in[3];
    const float* b2 = (const float*)d_in[4];
    const float* W3 = (const float*)d_in[5];
    const float* b3 = (const float*)d_in[6];
    const float* W4 = (const float*)d_in[7];
    const float* b4 = (const float*)d_in[8];
    float* out = (float*)d_out;

    half_t* wp = (half_t*)d_ws;

    hipLaunchKernelGGL(prep_w, dim3(624), dim3(256), 0, stream, W1, W2, W3, W4, wp);
    hipLaunchKernelGGL(mlp_mfma, dim3(M_TOTAL / 128), dim3(256), 0, stream,
                       x, wp, b1, b2, b3, b4, out);
}